// Round 5
// baseline (1710.661 us; speedup 1.0000x reference)
//
#include <hip/hip_runtime.h>
#include <hip/hip_bf16.h>
#include <math.h>

typedef __bf16 bf16x8_t __attribute__((ext_vector_type(8)));
typedef float f32x4_t __attribute__((ext_vector_type(4)));
typedef unsigned short u16x8_t __attribute__((ext_vector_type(8)));
typedef unsigned short u16x4_t __attribute__((ext_vector_type(4)));

#define DEV __device__ __forceinline__

DEV float bf2f(unsigned short u) {
    unsigned int v = ((unsigned int)u) << 16;
    return __builtin_bit_cast(float, v);
}
DEV unsigned short f2bf(float f) {
    unsigned int u = __builtin_bit_cast(unsigned int, f);
    u += 0x7fffu + ((u >> 16) & 1u);   // RNE
    return (unsigned short)(u >> 16);
}

// ---------------------------------------------------------------------------
// fp32 -> bf16 conversion (8 elems/thread)
// ---------------------------------------------------------------------------
__global__ __launch_bounds__(256) void cvt_k(
    const float* __restrict__ in, unsigned short* __restrict__ out, int n8)
{
    int t = blockIdx.x * 256 + threadIdx.x;
    if (t >= n8) return;
    f32x4_t a = ((const f32x4_t*)in)[t * 2];
    f32x4_t b = ((const f32x4_t*)in)[t * 2 + 1];
    u16x8_t o;
#pragma unroll
    for (int j = 0; j < 4; j++) { o[j] = f2bf(a[j]); o[4 + j] = f2bf(b[j]); }
    ((u16x8_t*)out)[t] = o;
}

// ---------------------------------------------------------------------------
// MFMA GEMM:  C[M x N] = A'[M x K] @ W[N x K]^T   (bf16 in, fp32 accum)
// 128x128 tile, BK=32, VGPR-mediated LDS staging.
// A' row remap (per-batch seq flip, row^4095) optional; C row flip optional;
// optional fp32 output / fp32 bias / accumulate-into-output.
// ---------------------------------------------------------------------------
template <bool FLIP_A, bool FLIP_C, bool OUT_F32, bool ADD_BIAS, bool ACCUM>
__global__ __launch_bounds__(256, 2) void gemm_bt(
    const unsigned short* __restrict__ A,
    const unsigned short* __restrict__ W,
    void* __restrict__ Cout,
    const float* __restrict__ bias,
    int N, int K, int ldc, int col_ofs)
{
    __shared__ __attribute__((aligned(16))) unsigned short lds[8192]; // A:[0,4096) W:[4096,8192)
    const int tid  = threadIdx.x;
    const int wave = tid >> 6;
    const int lane = tid & 63;
    const int mtile = blockIdx.y << 7;
    const int ntile = blockIdx.x << 7;

    const int r0 = tid >> 2, kg = tid & 3;
    const int r1 = r0 + 64;

    int am0 = mtile + r0; if (FLIP_A) am0 ^= 4095;
    int am1 = mtile + r1; if (FLIP_A) am1 ^= 4095;
    const unsigned short* aP0 = A + (size_t)am0 * K + kg * 8;
    const unsigned short* aP1 = A + (size_t)am1 * K + kg * 8;

    int wr0 = ntile + r0; if (wr0 > N - 1) wr0 = N - 1;
    int wr1 = ntile + r1; if (wr1 > N - 1) wr1 = N - 1;
    const unsigned short* wP0 = W + (size_t)wr0 * K + kg * 8;
    const unsigned short* wP1 = W + (size_t)wr1 * K + kg * 8;

    f32x4_t acc[4][4] = {};

    const int wm = (wave & 1) << 6;
    const int wn = (wave >> 1) << 6;
    const int r    = lane & 15;
    const int quad = lane >> 4;

    int aidx[4], widx[4];
#pragma unroll
    for (int i = 0; i < 4; i++) {
        aidx[i] = ((wm + i * 16 + r) * 4 + quad) * 8;
        widx[i] = 4096 + ((wn + i * 16 + r) * 4 + quad) * 8;
    }

    for (int k0 = 0; k0 < K; k0 += 32) {
        u16x8_t a0 = *(const u16x8_t*)(aP0 + k0);
        u16x8_t a1 = *(const u16x8_t*)(aP1 + k0);
        u16x8_t w0 = *(const u16x8_t*)(wP0 + k0);
        u16x8_t w1 = *(const u16x8_t*)(wP1 + k0);
        __syncthreads();
        *(u16x8_t*)&lds[tid * 8]                = a0;
        *(u16x8_t*)&lds[(tid + 256) * 8]        = a1;
        *(u16x8_t*)&lds[4096 + tid * 8]         = w0;
        *(u16x8_t*)&lds[4096 + (tid + 256) * 8] = w1;
        __syncthreads();

        bf16x8_t af[4], wf[4];
#pragma unroll
        for (int i = 0; i < 4; i++)
            af[i] = __builtin_bit_cast(bf16x8_t, *(const u16x8_t*)&lds[aidx[i]]);
#pragma unroll
        for (int j = 0; j < 4; j++)
            wf[j] = __builtin_bit_cast(bf16x8_t, *(const u16x8_t*)&lds[widx[j]]);
#pragma unroll
        for (int i = 0; i < 4; i++)
#pragma unroll
            for (int j = 0; j < 4; j++)
                acc[i][j] = __builtin_amdgcn_mfma_f32_16x16x32_bf16(af[i], wf[j], acc[i][j], 0, 0, 0);
    }

    // epilogue: C/D layout col=lane&15, row=quad*4+reg
#pragma unroll
    for (int i = 0; i < 4; i++) {
#pragma unroll
        for (int j = 0; j < 4; j++) {
            int cc = ntile + wn + j * 16 + r;
            if (cc >= N) continue;
#pragma unroll
            for (int reg = 0; reg < 4; reg++) {
                int rr = mtile + wm + i * 16 + quad * 4 + reg;
                int orow = FLIP_C ? (rr ^ 4095) : rr;
                float v = acc[i][j][reg];
                if (ADD_BIAS) v += bias[cc];
                if (OUT_F32) {
                    float* p = (float*)Cout + (size_t)orow * ldc + col_ofs + cc;
                    if (ACCUM) v += *p;
                    *p = v;
                } else {
                    ((unsigned short*)Cout)[(size_t)orow * ldc + col_ofs + cc] = f2bf(v);
                }
            }
        }
    }
}

// ---------------------------------------------------------------------------
// E[n][k] = sum_j proj_w[n][col_off+j] * out_proj[j][k]   (fp32 in, bf16 out)
// fuses out_proj + final proj: out_contrib = g_dir @ E_dir^T
// ---------------------------------------------------------------------------
__global__ __launch_bounds__(256) void eprep_k(
    const float* __restrict__ pw,
    const float* __restrict__ op,
    unsigned short* __restrict__ E, int col_off)
{
    int n = blockIdx.x;
    int k4 = threadIdx.x;
    float acc0 = 0.f, acc1 = 0.f, acc2 = 0.f, acc3 = 0.f;
    const float* pwr = pw + (size_t)n * 1024 + col_off;
    const float* opc = op + (k4 << 2);
#pragma unroll 4
    for (int j = 0; j < 512; j++) {
        float w = pwr[j];
        f32x4_t o = *(const f32x4_t*)(opc + ((size_t)j << 10));
        acc0 += w * o[0];
        acc1 += w * o[1];
        acc2 += w * o[2];
        acc3 += w * o[3];
    }
    u16x4_t e;
    e[0] = f2bf(acc0); e[1] = f2bf(acc1); e[2] = f2bf(acc2); e[3] = f2bf(acc3);
    *(u16x4_t*)(E + ((size_t)n << 10) + (k4 << 2)) = e;
}

// ---------------------------------------------------------------------------
// Depthwise causal conv (width 4, fp32 weights) + SiLU ; bf16 in/out
// ---------------------------------------------------------------------------
__global__ __launch_bounds__(256) void conv_silu_k(
    const unsigned short* __restrict__ xin,  // R x 1072 bf16
    const float* __restrict__ cw,            // 1056 x 4 fp32
    const float* __restrict__ cb,            // 1056 fp32
    unsigned short* __restrict__ outp)       // R x 1056 bf16
{
    int t = blockIdx.x * 256 + threadIdx.x;
    int c8 = t % 132;
    int row = t / 132;
    int l = row & 4095;
    int c = c8 * 8;
    float acc[8];
#pragma unroll
    for (int j = 0; j < 8; j++) acc[j] = cb[c + j];
#pragma unroll
    for (int k = 0; k < 4; k++) {
        int ls = l - 3 + k;
        if (ls < 0) continue;
        u16x8_t xv = *(const u16x8_t*)(xin + (size_t)(row - 3 + k) * 1072 + c);
#pragma unroll
        for (int j = 0; j < 8; j++)
            acc[j] += bf2f(xv[j]) * cw[(c + j) * 4 + k];
    }
    u16x8_t o;
#pragma unroll
    for (int j = 0; j < 8; j++) {
        float x = acc[j];
        o[j] = f2bf(x / (1.f + __expf(-x)));
    }
    *(u16x8_t*)(outp + (size_t)row * 1056 + c) = o;
}

// ---------------------------------------------------------------------------
// dt = softplus(dt_raw + dt_bias), dA = exp(dt * -exp(A_log))  (fp32 params)
// ---------------------------------------------------------------------------
__global__ __launch_bounds__(256) void dt_pre_k(
    const unsigned short* __restrict__ xin,  // R x 1072 bf16 (dt raw at 1056..1071)
    const float* __restrict__ dt_bias,
    const float* __restrict__ A_log,
    float* __restrict__ dtb, float* __restrict__ dab)
{
    int t = blockIdx.x * 256 + threadIdx.x;  // R*16
    int h = t & 15;
    int row = t >> 4;
    float x = bf2f(xin[(size_t)row * 1072 + 1056 + h]) + dt_bias[h];
    float dt = (x > 20.f) ? x : log1pf(__expf(x));
    float A = -__expf(A_log[h]);
    dtb[t] = dt;
    dab[t] = __expf(dt * A);
}

// ---------------------------------------------------------------------------
// Chunked scan, chunk=64. xconv row: [0,1024)=x heads, [1024,1040)=B, [1040,1056)=C
// ---------------------------------------------------------------------------
__global__ __launch_bounds__(64) void scan_state_k(
    const unsigned short* __restrict__ xc,
    const float* __restrict__ dtb, const float* __restrict__ dab,
    float* __restrict__ Hend, float* __restrict__ dec)
{
    int blk = blockIdx.x;
    int chunk = blk & 63;
    int bh = blk >> 6;
    int h = bh & 15, b = bh >> 4;
    int p = threadIdx.x;
    float hs[16];
#pragma unroll
    for (int n = 0; n < 16; n++) hs[n] = 0.f;
    float decay = 1.f;
    int row0 = b * 4096 + chunk * 64;
#pragma unroll 2
    for (int t = 0; t < 64; t++) {
        int row = row0 + t;
        const unsigned short* xr = xc + (size_t)row * 1056;
        float xp = bf2f(xr[h * 64 + p]);
        u16x8_t b0 = *(const u16x8_t*)(xr + 1024);
        u16x8_t b1 = *(const u16x8_t*)(xr + 1032);
        float dt = dtb[row * 16 + h];
        float dA = dab[row * 16 + h];
        float coef = dt * xp;
#pragma unroll
        for (int n = 0; n < 8; n++) hs[n] = fmaf(hs[n], dA, coef * bf2f(b0[n]));
#pragma unroll
        for (int n = 0; n < 8; n++) hs[8 + n] = fmaf(hs[8 + n], dA, coef * bf2f(b1[n]));
        decay *= dA;
    }
    float* o = Hend + (size_t)blk * 1024 + p * 16;
#pragma unroll
    for (int n = 0; n < 16; n++) o[n] = hs[n];
    if (p == 0) dec[blk] = decay;
}

__global__ __launch_bounds__(64) void scan_comb_k(float* __restrict__ H, const float* __restrict__ dec)
{
    int bh = blockIdx.x;
    int p = threadIdx.x;
    float hs[16];
#pragma unroll
    for (int n = 0; n < 16; n++) hs[n] = 0.f;
    for (int c = 0; c < 64; c++) {
        float* ptr = H + (size_t)(bh * 64 + c) * 1024 + p * 16;
        float tmp[16];
#pragma unroll
        for (int n = 0; n < 16; n++) tmp[n] = ptr[n];
        float d = dec[bh * 64 + c];
#pragma unroll
        for (int n = 0; n < 16; n++) { ptr[n] = hs[n]; hs[n] = fmaf(hs[n], d, tmp[n]); }
    }
}

__global__ __launch_bounds__(64) void scan_out_k(
    const unsigned short* __restrict__ xc,
    const float* __restrict__ dtb, const float* __restrict__ dab,
    const float* __restrict__ Hst,
    const float* __restrict__ Dp,
    unsigned short* __restrict__ ybuf)  // R x 1024 bf16
{
    int blk = blockIdx.x;
    int chunk = blk & 63;
    int bh = blk >> 6;
    int h = bh & 15, b = bh >> 4;
    int p = threadIdx.x;
    float hs[16];
    const float* hi = Hst + (size_t)blk * 1024 + p * 16;
#pragma unroll
    for (int n = 0; n < 16; n++) hs[n] = hi[n];
    float Dh = Dp[h];
    int row0 = b * 4096 + chunk * 64;
#pragma unroll 2
    for (int t = 0; t < 64; t++) {
        int row = row0 + t;
        const unsigned short* xr = xc + (size_t)row * 1056;
        float xp = bf2f(xr[h * 64 + p]);
        u16x8_t b0 = *(const u16x8_t*)(xr + 1024);
        u16x8_t b1 = *(const u16x8_t*)(xr + 1032);
        u16x8_t c0 = *(const u16x8_t*)(xr + 1040);
        u16x8_t c1 = *(const u16x8_t*)(xr + 1048);
        float dt = dtb[row * 16 + h];
        float dA = dab[row * 16 + h];
        float coef = dt * xp;
        float yp = 0.f;
#pragma unroll
        for (int n = 0; n < 8; n++) {
            hs[n] = fmaf(hs[n], dA, coef * bf2f(b0[n]));
            yp = fmaf(hs[n], bf2f(c0[n]), yp);
        }
#pragma unroll
        for (int n = 0; n < 8; n++) {
            hs[8 + n] = fmaf(hs[8 + n], dA, coef * bf2f(b1[n]));
            yp = fmaf(hs[8 + n], bf2f(c1[n]), yp);
        }
        yp = fmaf(Dh, xp, yp);
        ybuf[(size_t)row * 1024 + h * 64 + p] = f2bf(yp);
    }
}

// ---------------------------------------------------------------------------
// Gated RMSNorm (in-place on y, bf16): norm_w fp32
// ---------------------------------------------------------------------------
__global__ __launch_bounds__(256) void rmsgate_k(
    unsigned short* __restrict__ y,
    const unsigned short* __restrict__ z,
    const float* __restrict__ nw)
{
    __shared__ float sred[256];
    int row = blockIdx.x;
    int t = threadIdx.x;
    int c = t * 4;
    u16x4_t yv = *(const u16x4_t*)(y + (size_t)row * 1024 + c);
    u16x4_t zv = *(const u16x4_t*)(z + (size_t)row * 1024 + c);
    float g[4];
    float ss = 0.f;
#pragma unroll
    for (int j = 0; j < 4; j++) {
        float zf = bf2f(zv[j]);
        float sil = zf / (1.f + __expf(-zf));
        g[j] = bf2f(yv[j]) * sil;
        ss += g[j] * g[j];
    }
    sred[t] = ss;
    __syncthreads();
#pragma unroll
    for (int s = 128; s > 0; s >>= 1) {
        if (t < s) sred[t] += sred[t + s];
        __syncthreads();
    }
    float scale = rsqrtf(sred[0] * (1.f / 1024.f) + 1e-5f);
    u16x4_t o4;
#pragma unroll
    for (int j = 0; j < 4; j++) o4[j] = f2bf(g[j] * scale * nw[c + j]);
    *(u16x4_t*)(y + (size_t)row * 1024 + c) = o4;
}

// ---------------------------------------------------------------------------
// Final: out = LayerNorm(x + f)  — all fp32 I/O
// ---------------------------------------------------------------------------
__global__ __launch_bounds__(128) void ln_k(
    const float* __restrict__ x,   // R x 512 fp32
    const float* __restrict__ f,   // R x 512 fp32
    const float* __restrict__ lw,
    const float* __restrict__ lb,
    float* __restrict__ outp)      // R x 512 fp32
{
    __shared__ float sA[128], sB[128];
    int row = blockIdx.x;
    int t = threadIdx.x;
    int c = t * 4;
    float s[4];
    float sum = 0.f, sq = 0.f;
    f32x4_t xv = *(const f32x4_t*)(x + (size_t)row * 512 + c);
    f32x4_t fv = *(const f32x4_t*)(f + (size_t)row * 512 + c);
#pragma unroll
    for (int j = 0; j < 4; j++) {
        s[j] = xv[j] + fv[j];
        sum += s[j];
        sq += s[j] * s[j];
    }
    sA[t] = sum; sB[t] = sq;
    __syncthreads();
#pragma unroll
    for (int st = 64; st > 0; st >>= 1) {
        if (t < st) { sA[t] += sA[t + st]; sB[t] += sB[t + st]; }
        __syncthreads();
    }
    float mu = sA[0] * (1.f / 512.f);
    float var = sB[0] * (1.f / 512.f) - mu * mu;
    if (var < 0.f) var = 0.f;
    float inv = rsqrtf(var + 1e-5f);
    f32x4_t o4;
#pragma unroll
    for (int j = 0; j < 4; j++)
        o4[j] = (s[j] - mu) * inv * lw[c + j] + lb[c + j];
    *(f32x4_t*)(outp + (size_t)row * 512 + c) = o4;
}

// ---------------------------------------------------------------------------
extern "C" void kernel_launch(void* const* d_in, const int* in_sizes, int n_in,
                              void* d_out, int out_size, void* d_ws, size_t ws_size,
                              hipStream_t stream)
{
    (void)in_sizes; (void)n_in; (void)out_size;

    const float* x           = (const float*)d_in[0];
    const float* in_proj[2]  = {(const float*)d_in[1],  (const float*)d_in[9]};
    const float* conv_w[2]   = {(const float*)d_in[2],  (const float*)d_in[10]};
    const float* conv_b[2]   = {(const float*)d_in[3],  (const float*)d_in[11]};
    const float* dt_bias[2]  = {(const float*)d_in[4],  (const float*)d_in[12]};
    const float* A_log[2]    = {(const float*)d_in[5],  (const float*)d_in[13]};
    const float* Dp[2]       = {(const float*)d_in[6],  (const float*)d_in[14]};
    const float* norm_w[2]   = {(const float*)d_in[7],  (const float*)d_in[15]};
    const float* out_proj[2] = {(const float*)d_in[8],  (const float*)d_in[16]};
    const float* proj_w      = (const float*)d_in[17];
    const float* proj_b      = (const float*)d_in[18];
    const float* ln_w        = (const float*)d_in[19];
    const float* ln_b        = (const float*)d_in[20];
    float* outp = (float*)d_out;

    const size_t IP_ELEMS = (size_t)2096 * 512;   // in_proj elements
    const size_t X_ELEMS  = (size_t)32768 * 512;

    // ---- adaptive batch grouping ----
    // constant: xb16 64MB/2 + 2*in_proj_bf16 + Ebuf
    // per-row: xbcdt 2144 + xconv 2112 + fbuf 2048 + dtb 64 + dab 64 + Hbuf 1024
    const size_t constBytes = X_ELEMS * 2 + 2 * IP_ELEMS * 2 + 2 * 512 * 1024 * 2 + 4096;
    int g = 1;
    {
        const int cands[3] = {8, 4, 2};
        for (int ci = 0; ci < 3; ci++) {
            size_t R = (size_t)cands[ci] * 4096;
            size_t need = constBytes + R * (2144 + 2112 + 2048 + 64 + 64 + 1024)
                        + (size_t)cands[ci] * 1024 * 4 + 16 * 256;
            if (need <= ws_size) { g = cands[ci]; break; }
        }
    }
    const size_t R = (size_t)g * 4096;
    const int nGroups = 8 / g;
    const int MT = (int)(R >> 7);

    char* ws = (char*)d_ws;
    size_t off = 0;
    auto alloc = [&](size_t bytes) -> char* {
        char* p = ws + off;
        off += (bytes + 255) & ~(size_t)255;
        return p;
    };
    unsigned short* xb16  = (unsigned short*)alloc(X_ELEMS * 2);
    unsigned short* ipb16[2];
    ipb16[0] = (unsigned short*)alloc(IP_ELEMS * 2);
    ipb16[1] = (unsigned short*)alloc(IP_ELEMS * 2);
    unsigned short* Ebuf  = (unsigned short*)alloc(2 * 512 * 1024 * 2);
    unsigned short* Ef    = Ebuf;
    unsigned short* Eb    = Ebuf + 512 * 1024;
    unsigned short* xbcdt = (unsigned short*)alloc(R * 1072 * 2);
    unsigned short* ybuf  = xbcdt;                       // alias (xbcdt dead by scan_out)
    unsigned short* xconv = (unsigned short*)alloc(R * 1056 * 2);
    unsigned short* zbuf  = xconv;                       // alias (xconv dead after scans)
    float* fbuf = (float*)alloc(R * 512 * 4);
    float* dtb  = (float*)alloc(R * 16 * 4);
    float* dab  = (float*)alloc(R * 16 * 4);
    float* Hbuf = (float*)alloc(R * 1024);
    float* dec  = (float*)alloc((size_t)g * 1024 * 4);

    dim3 blk(256);

    // ---- one-time conversions + E prep ----
    cvt_k<<<(unsigned)((X_ELEMS / 8 + 255) / 256), blk, 0, stream>>>(x, xb16, (int)(X_ELEMS / 8));
    cvt_k<<<(unsigned)((IP_ELEMS / 8 + 255) / 256), blk, 0, stream>>>(in_proj[0], ipb16[0], (int)(IP_ELEMS / 8));
    cvt_k<<<(unsigned)((IP_ELEMS / 8 + 255) / 256), blk, 0, stream>>>(in_proj[1], ipb16[1], (int)(IP_ELEMS / 8));
    eprep_k<<<512, blk, 0, stream>>>(proj_w, out_proj[0], Ef, 0);
    eprep_k<<<512, blk, 0, stream>>>(proj_w, out_proj[1], Eb, 512);

    for (int grp = 0; grp < nGroups; grp++) {
        const unsigned short* xg = xb16 + (size_t)grp * R * 512;
        const float* xgf = x + (size_t)grp * R * 512;
        float* og = outp + (size_t)grp * R * 512;

        for (int dir = 0; dir < 2; dir++) {
            // in_proj xBC|dt part: [R x 1072]
            if (dir == 0)
                gemm_bt<false, false, false, false, false><<<dim3(9, MT), blk, 0, stream>>>(
                    xg, ipb16[0] + (size_t)1024 * 512, xbcdt, nullptr, 1072, 512, 1072, 0);
            else
                gemm_bt<true, false, false, false, false><<<dim3(9, MT), blk, 0, stream>>>(
                    xg, ipb16[1] + (size_t)1024 * 512, xbcdt, nullptr, 1072, 512, 1072, 0);

            conv_silu_k<<<(unsigned)(R * 132 / 256), blk, 0, stream>>>(xbcdt, conv_w[dir], conv_b[dir], xconv);
            dt_pre_k<<<(unsigned)(R * 16 / 256), blk, 0, stream>>>(xbcdt, dt_bias[dir], A_log[dir], dtb, dab);

            scan_state_k<<<(unsigned)(R / 4), dim3(64), 0, stream>>>(xconv, dtb, dab, Hbuf, dec);
            scan_comb_k<<<(unsigned)(g * 16), dim3(64), 0, stream>>>(Hbuf, dec);
            scan_out_k<<<(unsigned)(R / 4), dim3(64), 0, stream>>>(xconv, dtb, dab, Hbuf, Dp[dir], ybuf);

            // in_proj z part into zbuf (= xconv region, now dead)
            if (dir == 0)
                gemm_bt<false, false, false, false, false><<<dim3(8, MT), blk, 0, stream>>>(
                    xg, ipb16[0], zbuf, nullptr, 1024, 512, 1024, 0);
            else
                gemm_bt<true, false, false, false, false><<<dim3(8, MT), blk, 0, stream>>>(
                    xg, ipb16[1], zbuf, nullptr, 1024, 512, 1024, 0);

            rmsgate_k<<<(unsigned)R, blk, 0, stream>>>(ybuf, zbuf, norm_w[dir]);

            // fused out_proj+proj: fbuf (+)= g_dir @ E_dir^T
            if (dir == 0)
                gemm_bt<false, false, true, true, false><<<dim3(4, MT), blk, 0, stream>>>(
                    ybuf, Ef, fbuf, proj_b, 512, 1024, 512, 0);
            else
                gemm_bt<false, true, true, false, true><<<dim3(4, MT), blk, 0, stream>>>(
                    ybuf, Eb, fbuf, nullptr, 512, 1024, 512, 0);
        }
        ln_k<<<(unsigned)R, dim3(128), 0, stream>>>(xgf, fbuf, ln_w, ln_b, og);
    }
}

// Round 6
// 1291.854 us; speedup vs baseline: 1.3242x; 1.3242x over previous
//
#include <hip/hip_runtime.h>
#include <hip/hip_bf16.h>
#include <math.h>

typedef __bf16 bf16x8_t __attribute__((ext_vector_type(8)));
typedef float f32x4_t __attribute__((ext_vector_type(4)));
typedef unsigned short u16x8_t __attribute__((ext_vector_type(8)));
typedef unsigned short u16x4_t __attribute__((ext_vector_type(4)));

#define DEV __device__ __forceinline__

DEV float bf2f(unsigned short u) {
    unsigned int v = ((unsigned int)u) << 16;
    return __builtin_bit_cast(float, v);
}
DEV unsigned short f2bf(float f) {
    unsigned int u = __builtin_bit_cast(unsigned int, f);
    u += 0x7fffu + ((u >> 16) & 1u);   // RNE
    return (unsigned short)(u >> 16);
}

// ---------------------------------------------------------------------------
// fp32 -> bf16 conversion (8 elems/thread)
// ---------------------------------------------------------------------------
__global__ __launch_bounds__(256) void cvt_k(
    const float* __restrict__ in, unsigned short* __restrict__ out, int n8)
{
    int t = blockIdx.x * 256 + threadIdx.x;
    if (t >= n8) return;
    f32x4_t a = ((const f32x4_t*)in)[t * 2];
    f32x4_t b = ((const f32x4_t*)in)[t * 2 + 1];
    u16x8_t o;
#pragma unroll
    for (int j = 0; j < 4; j++) { o[j] = f2bf(a[j]); o[4 + j] = f2bf(b[j]); }
    ((u16x8_t*)out)[t] = o;
}

// ---------------------------------------------------------------------------
// MFMA GEMM:  C[M x N] = A'[M x K] @ W[N x K]^T   (bf16 in, fp32 accum)
// 128x128 tile, BK=32, global_load_lds width-16 staging, XOR-swizzled chunks.
// staging: chunk c (0..511) -> row=c>>2, pos=c&3; holds kgroup g = pos ^ ((row>>1)&3)
// ---------------------------------------------------------------------------
template <bool FLIP_A, bool FLIP_C, bool OUT_F32, bool ADD_BIAS, bool ACCUM>
__global__ __launch_bounds__(256, 2) void gemm_bt(
    const unsigned short* __restrict__ A,
    const unsigned short* __restrict__ W,
    void* __restrict__ Cout,
    const float* __restrict__ bias,
    int N, int K, int ldc, int col_ofs)
{
    __shared__ __attribute__((aligned(16))) unsigned char smem[16384]; // A: 8KB, W: 8KB
    const int tid  = threadIdx.x;
    const int wave = tid >> 6;
    const int lane = tid & 63;
    const int mtile = blockIdx.y << 7;
    const int ntile = blockIdx.x << 7;

    const int c0 = tid, c1 = 256 + tid;
    const int r0 = c0 >> 2, p0 = c0 & 3, g0 = p0 ^ ((r0 >> 1) & 3);
    const int r1 = c1 >> 2, p1 = c1 & 3, g1 = p1 ^ ((r1 >> 1) & 3);

    int am0 = mtile + r0; if (FLIP_A) am0 ^= 4095;
    int am1 = mtile + r1; if (FLIP_A) am1 ^= 4095;
    const unsigned short* aP0 = A + (size_t)am0 * K + g0 * 8;
    const unsigned short* aP1 = A + (size_t)am1 * K + g1 * 8;

    int wr0 = ntile + r0; if (wr0 > N - 1) wr0 = N - 1;
    int wr1 = ntile + r1; if (wr1 > N - 1) wr1 = N - 1;
    const unsigned short* wP0 = W + (size_t)wr0 * K + g0 * 8;
    const unsigned short* wP1 = W + (size_t)wr1 * K + g1 * 8;

    unsigned char* ldsA = smem;
    unsigned char* ldsW = smem + 8192;
    unsigned char* ldsA0 = ldsA + wave * 1024;          // wave-uniform bases
    unsigned char* ldsA1 = ldsA + 4096 + wave * 1024;
    unsigned char* ldsW0 = ldsW + wave * 1024;
    unsigned char* ldsW1 = ldsW + 4096 + wave * 1024;

    f32x4_t acc[4][4] = {};

    const int wm = (wave & 1) << 6;
    const int wn = (wave >> 1) << 6;
    const int r    = lane & 15;
    const int quad = lane >> 4;
    const int sw   = (r >> 1) & 3;

    int aoff[4], woff[4];
#pragma unroll
    for (int i = 0; i < 4; i++) {
        int m = wm + i * 16 + r;
        aoff[i] = (m * 4 + (quad ^ sw)) * 16;
        int n = wn + i * 16 + r;
        woff[i] = (n * 4 + (quad ^ sw)) * 16;
    }

    for (int k0 = 0; k0 < K; k0 += 32) {
        __builtin_amdgcn_global_load_lds(
            (const __attribute__((address_space(1))) void*)(aP0 + k0),
            (__attribute__((address_space(3))) void*)ldsA0, 16, 0, 0);
        __builtin_amdgcn_global_load_lds(
            (const __attribute__((address_space(1))) void*)(aP1 + k0),
            (__attribute__((address_space(3))) void*)ldsA1, 16, 0, 0);
        __builtin_amdgcn_global_load_lds(
            (const __attribute__((address_space(1))) void*)(wP0 + k0),
            (__attribute__((address_space(3))) void*)ldsW0, 16, 0, 0);
        __builtin_amdgcn_global_load_lds(
            (const __attribute__((address_space(1))) void*)(wP1 + k0),
            (__attribute__((address_space(3))) void*)ldsW1, 16, 0, 0);
        __syncthreads();

        bf16x8_t af[4], wf[4];
#pragma unroll
        for (int i = 0; i < 4; i++)
            af[i] = __builtin_bit_cast(bf16x8_t, *(const u16x8_t*)(ldsA + aoff[i]));
#pragma unroll
        for (int j = 0; j < 4; j++)
            wf[j] = __builtin_bit_cast(bf16x8_t, *(const u16x8_t*)(ldsW + woff[j]));
#pragma unroll
        for (int i = 0; i < 4; i++)
#pragma unroll
            for (int j = 0; j < 4; j++)
                acc[i][j] = __builtin_amdgcn_mfma_f32_16x16x32_bf16(af[i], wf[j], acc[i][j], 0, 0, 0);
        __syncthreads();
    }

    // epilogue: C/D layout col=lane&15, row=quad*4+reg
#pragma unroll
    for (int i = 0; i < 4; i++) {
#pragma unroll
        for (int j = 0; j < 4; j++) {
            int cc = ntile + wn + j * 16 + r;
            if (cc >= N) continue;
#pragma unroll
            for (int reg = 0; reg < 4; reg++) {
                int rr = mtile + wm + i * 16 + quad * 4 + reg;
                int orow = FLIP_C ? (rr ^ 4095) : rr;
                float v = acc[i][j][reg];
                if (ADD_BIAS) v += bias[cc];
                if (OUT_F32) {
                    float* p = (float*)Cout + (size_t)orow * ldc + col_ofs + cc;
                    if (ACCUM) v += *p;
                    *p = v;
                } else {
                    ((unsigned short*)Cout)[(size_t)orow * ldc + col_ofs + cc] = f2bf(v);
                }
            }
        }
    }
}

// ---------------------------------------------------------------------------
// E[n][k] = sum_j proj_w[n][col_off+j] * out_proj[j][k]   (fp32 in, bf16 out)
// ---------------------------------------------------------------------------
__global__ __launch_bounds__(256) void eprep_k(
    const float* __restrict__ pw,
    const float* __restrict__ op,
    unsigned short* __restrict__ E, int col_off)
{
    int n = blockIdx.x;
    int k4 = threadIdx.x;
    float acc0 = 0.f, acc1 = 0.f, acc2 = 0.f, acc3 = 0.f;
    const float* pwr = pw + (size_t)n * 1024 + col_off;
    const float* opc = op + (k4 << 2);
#pragma unroll 4
    for (int j = 0; j < 512; j++) {
        float w = pwr[j];
        f32x4_t o = *(const f32x4_t*)(opc + ((size_t)j << 10));
        acc0 += w * o[0];
        acc1 += w * o[1];
        acc2 += w * o[2];
        acc3 += w * o[3];
    }
    u16x4_t e;
    e[0] = f2bf(acc0); e[1] = f2bf(acc1); e[2] = f2bf(acc2); e[3] = f2bf(acc3);
    *(u16x4_t*)(E + ((size_t)n << 10) + (k4 << 2)) = e;
}

// ---------------------------------------------------------------------------
// Depthwise causal conv (width 4) + SiLU, 8 rows/thread sliding window.
// thread: c8 = t%132 (8 channels), rb = t/132 (8 rows rb*8..rb*8+7)
// ---------------------------------------------------------------------------
__global__ __launch_bounds__(256) void conv_silu_k(
    const unsigned short* __restrict__ xin,  // R x 1072 bf16
    const float* __restrict__ cw,            // 1056 x 4 fp32
    const float* __restrict__ cb,            // 1056 fp32
    unsigned short* __restrict__ outp)       // R x 1056 bf16
{
    int t = blockIdx.x * 256 + threadIdx.x;
    int c8 = t % 132;
    int rb = t / 132;
    int c = c8 * 8;
    int row0 = rb * 8;
    int l0 = row0 & 4095;

    float w[8][4];
#pragma unroll
    for (int j = 0; j < 8; j++) {
        f32x4_t wv = *(const f32x4_t*)(cw + (c + j) * 4);
        w[j][0] = wv[0]; w[j][1] = wv[1]; w[j][2] = wv[2]; w[j][3] = wv[3];
    }
    float bia[8];
    {
        f32x4_t b0 = *(const f32x4_t*)(cb + c);
        f32x4_t b1 = *(const f32x4_t*)(cb + c + 4);
#pragma unroll
        for (int j = 0; j < 4; j++) { bia[j] = b0[j]; bia[4 + j] = b1[j]; }
    }

    u16x8_t zero;
#pragma unroll
    for (int j = 0; j < 8; j++) zero[j] = 0;

    // window rows row0-3 .. row0+7 (11 rows); pre-batch rows are zero
    u16x8_t win[11];
#pragma unroll
    for (int u = 0; u < 11; u++) {
        int lu = l0 - 3 + u;
        win[u] = (lu >= 0)
            ? *(const u16x8_t*)(xin + (size_t)(row0 - 3 + u) * 1072 + c)
            : zero;
    }

#pragma unroll
    for (int s = 0; s < 8; s++) {
        float acc[8];
#pragma unroll
        for (int j = 0; j < 8; j++) acc[j] = bia[j];
#pragma unroll
        for (int k = 0; k < 4; k++) {
            u16x8_t xv = win[s + k];
#pragma unroll
            for (int j = 0; j < 8; j++)
                acc[j] = fmaf(bf2f(xv[j]), w[j][k], acc[j]);
        }
        u16x8_t o;
#pragma unroll
        for (int j = 0; j < 8; j++) {
            float xx = acc[j];
            o[j] = f2bf(xx * __builtin_amdgcn_rcpf(1.f + __expf(-xx)));
        }
        *(u16x8_t*)(outp + (size_t)(row0 + s) * 1056 + c) = o;
    }
}

// ---------------------------------------------------------------------------
// dt = softplus(dt_raw + dt_bias), dA = exp(dt * -exp(A_log))  (fp32 params)
// ---------------------------------------------------------------------------
__global__ __launch_bounds__(256) void dt_pre_k(
    const unsigned short* __restrict__ xin,  // R x 1072 bf16 (dt raw at 1056..1071)
    const float* __restrict__ dt_bias,
    const float* __restrict__ A_log,
    float* __restrict__ dtb, float* __restrict__ dab)
{
    int t = blockIdx.x * 256 + threadIdx.x;  // R*16
    int h = t & 15;
    int row = t >> 4;
    float x = bf2f(xin[(size_t)row * 1072 + 1056 + h]) + dt_bias[h];
    float dt = (x > 20.f) ? x : log1pf(__expf(x));
    float A = -__expf(A_log[h]);
    dtb[t] = dt;
    dab[t] = __expf(dt * A);
}

// ---------------------------------------------------------------------------
// Chunked scan, chunk=64. xconv row: [0,1024)=x heads, [1024,1040)=B, [1040,1056)=C
// ---------------------------------------------------------------------------
__global__ __launch_bounds__(64) void scan_state_k(
    const unsigned short* __restrict__ xc,
    const float* __restrict__ dtb, const float* __restrict__ dab,
    float* __restrict__ Hend, float* __restrict__ dec)
{
    int blk = blockIdx.x;
    int chunk = blk & 63;
    int bh = blk >> 6;
    int h = bh & 15, b = bh >> 4;
    int p = threadIdx.x;
    float hs[16];
#pragma unroll
    for (int n = 0; n < 16; n++) hs[n] = 0.f;
    float decay = 1.f;
    int row0 = b * 4096 + chunk * 64;
#pragma unroll 2
    for (int t = 0; t < 64; t++) {
        int row = row0 + t;
        const unsigned short* xr = xc + (size_t)row * 1056;
        float xp = bf2f(xr[h * 64 + p]);
        u16x8_t b0 = *(const u16x8_t*)(xr + 1024);
        u16x8_t b1 = *(const u16x8_t*)(xr + 1032);
        float dt = dtb[row * 16 + h];
        float dA = dab[row * 16 + h];
        float coef = dt * xp;
#pragma unroll
        for (int n = 0; n < 8; n++) hs[n] = fmaf(hs[n], dA, coef * bf2f(b0[n]));
#pragma unroll
        for (int n = 0; n < 8; n++) hs[8 + n] = fmaf(hs[8 + n], dA, coef * bf2f(b1[n]));
        decay *= dA;
    }
    float* o = Hend + (size_t)blk * 1024 + p * 16;
#pragma unroll
    for (int n = 0; n < 16; n++) o[n] = hs[n];
    if (p == 0) dec[blk] = decay;
}

__global__ __launch_bounds__(64) void scan_comb_k(float* __restrict__ H, const float* __restrict__ dec)
{
    int bh = blockIdx.x;
    int p = threadIdx.x;
    float hs[16];
#pragma unroll
    for (int n = 0; n < 16; n++) hs[n] = 0.f;
    for (int c = 0; c < 64; c++) {
        float* ptr = H + (size_t)(bh * 64 + c) * 1024 + p * 16;
        float tmp[16];
#pragma unroll
        for (int n = 0; n < 16; n++) tmp[n] = ptr[n];
        float d = dec[bh * 64 + c];
#pragma unroll
        for (int n = 0; n < 16; n++) { ptr[n] = hs[n]; hs[n] = fmaf(hs[n], d, tmp[n]); }
    }
}

__global__ __launch_bounds__(64) void scan_out_k(
    const unsigned short* __restrict__ xc,
    const float* __restrict__ dtb, const float* __restrict__ dab,
    const float* __restrict__ Hst,
    const float* __restrict__ Dp,
    unsigned short* __restrict__ ybuf)  // R x 1024 bf16
{
    int blk = blockIdx.x;
    int chunk = blk & 63;
    int bh = blk >> 6;
    int h = bh & 15, b = bh >> 4;
    int p = threadIdx.x;
    float hs[16];
    const float* hi = Hst + (size_t)blk * 1024 + p * 16;
#pragma unroll
    for (int n = 0; n < 16; n++) hs[n] = hi[n];
    float Dh = Dp[h];
    int row0 = b * 4096 + chunk * 64;
#pragma unroll 2
    for (int t = 0; t < 64; t++) {
        int row = row0 + t;
        const unsigned short* xr = xc + (size_t)row * 1056;
        float xp = bf2f(xr[h * 64 + p]);
        u16x8_t b0 = *(const u16x8_t*)(xr + 1024);
        u16x8_t b1 = *(const u16x8_t*)(xr + 1032);
        u16x8_t c0 = *(const u16x8_t*)(xr + 1040);
        u16x8_t c1 = *(const u16x8_t*)(xr + 1048);
        float dt = dtb[row * 16 + h];
        float dA = dab[row * 16 + h];
        float coef = dt * xp;
        float yp = 0.f;
#pragma unroll
        for (int n = 0; n < 8; n++) {
            hs[n] = fmaf(hs[n], dA, coef * bf2f(b0[n]));
            yp = fmaf(hs[n], bf2f(c0[n]), yp);
        }
#pragma unroll
        for (int n = 0; n < 8; n++) {
            hs[8 + n] = fmaf(hs[8 + n], dA, coef * bf2f(b1[n]));
            yp = fmaf(hs[8 + n], bf2f(c1[n]), yp);
        }
        yp = fmaf(Dh, xp, yp);
        ybuf[(size_t)row * 1024 + h * 64 + p] = f2bf(yp);
    }
}

// ---------------------------------------------------------------------------
// Gated RMSNorm (in-place on y, bf16): norm_w fp32
// ---------------------------------------------------------------------------
__global__ __launch_bounds__(256) void rmsgate_k(
    unsigned short* __restrict__ y,
    const unsigned short* __restrict__ z,
    const float* __restrict__ nw)
{
    __shared__ float sred[256];
    int row = blockIdx.x;
    int t = threadIdx.x;
    int c = t * 4;
    u16x4_t yv = *(const u16x4_t*)(y + (size_t)row * 1024 + c);
    u16x4_t zv = *(const u16x4_t*)(z + (size_t)row * 1024 + c);
    float g[4];
    float ss = 0.f;
#pragma unroll
    for (int j = 0; j < 4; j++) {
        float zf = bf2f(zv[j]);
        float sil = zf * __builtin_amdgcn_rcpf(1.f + __expf(-zf));
        g[j] = bf2f(yv[j]) * sil;
        ss += g[j] * g[j];
    }
    sred[t] = ss;
    __syncthreads();
#pragma unroll
    for (int s = 128; s > 0; s >>= 1) {
        if (t < s) sred[t] += sred[t + s];
        __syncthreads();
    }
    float scale = rsqrtf(sred[0] * (1.f / 1024.f) + 1e-5f);
    u16x4_t o4;
#pragma unroll
    for (int j = 0; j < 4; j++) o4[j] = f2bf(g[j] * scale * nw[c + j]);
    *(u16x4_t*)(y + (size_t)row * 1024 + c) = o4;
}

// ---------------------------------------------------------------------------
// Final: out = LayerNorm(x + f)  — all fp32 I/O
// ---------------------------------------------------------------------------
__global__ __launch_bounds__(128) void ln_k(
    const float* __restrict__ x,   // R x 512 fp32
    const float* __restrict__ f,   // R x 512 fp32
    const float* __restrict__ lw,
    const float* __restrict__ lb,
    float* __restrict__ outp)      // R x 512 fp32
{
    __shared__ float sA[128], sB[128];
    int row = blockIdx.x;
    int t = threadIdx.x;
    int c = t * 4;
    float s[4];
    float sum = 0.f, sq = 0.f;
    f32x4_t xv = *(const f32x4_t*)(x + (size_t)row * 512 + c);
    f32x4_t fv = *(const f32x4_t*)(f + (size_t)row * 512 + c);
#pragma unroll
    for (int j = 0; j < 4; j++) {
        s[j] = xv[j] + fv[j];
        sum += s[j];
        sq += s[j] * s[j];
    }
    sA[t] = sum; sB[t] = sq;
    __syncthreads();
#pragma unroll
    for (int st = 64; st > 0; st >>= 1) {
        if (t < st) { sA[t] += sA[t + st]; sB[t] += sB[t + st]; }
        __syncthreads();
    }
    float mu = sA[0] * (1.f / 512.f);
    float var = sB[0] * (1.f / 512.f) - mu * mu;
    if (var < 0.f) var = 0.f;
    float inv = rsqrtf(var + 1e-5f);
    f32x4_t o4;
#pragma unroll
    for (int j = 0; j < 4; j++)
        o4[j] = (s[j] - mu) * inv * lw[c + j] + lb[c + j];
    *(f32x4_t*)(outp + (size_t)row * 512 + c) = o4;
}

// ---------------------------------------------------------------------------
extern "C" void kernel_launch(void* const* d_in, const int* in_sizes, int n_in,
                              void* d_out, int out_size, void* d_ws, size_t ws_size,
                              hipStream_t stream)
{
    (void)in_sizes; (void)n_in; (void)out_size;

    const float* x           = (const float*)d_in[0];
    const float* in_proj[2]  = {(const float*)d_in[1],  (const float*)d_in[9]};
    const float* conv_w[2]   = {(const float*)d_in[2],  (const float*)d_in[10]};
    const float* conv_b[2]   = {(const float*)d_in[3],  (const float*)d_in[11]};
    const float* dt_bias[2]  = {(const float*)d_in[4],  (const float*)d_in[12]};
    const float* A_log[2]    = {(const float*)d_in[5],  (const float*)d_in[13]};
    const float* Dp[2]       = {(const float*)d_in[6],  (const float*)d_in[14]};
    const float* norm_w[2]   = {(const float*)d_in[7],  (const float*)d_in[15]};
    const float* out_proj[2] = {(const float*)d_in[8],  (const float*)d_in[16]};
    const float* proj_w      = (const float*)d_in[17];
    const float* proj_b      = (const float*)d_in[18];
    const float* ln_w        = (const float*)d_in[19];
    const float* ln_b        = (const float*)d_in[20];
    float* outp = (float*)d_out;

    const size_t IP_ELEMS = (size_t)2096 * 512;
    const size_t X_ELEMS  = (size_t)32768 * 512;

    const size_t constBytes = X_ELEMS * 2 + 2 * IP_ELEMS * 2 + 2 * 512 * 1024 * 2 + 4096;
    int g = 1;
    {
        const int cands[3] = {8, 4, 2};
        for (int ci = 0; ci < 3; ci++) {
            size_t R = (size_t)cands[ci] * 4096;
            size_t need = constBytes + R * (2144 + 2112 + 2048 + 64 + 64 + 1024)
                        + (size_t)cands[ci] * 1024 * 4 + 16 * 256;
            if (need <= ws_size) { g = cands[ci]; break; }
        }
    }
    const size_t R = (size_t)g * 4096;
    const int nGroups = 8 / g;
    const int MT = (int)(R >> 7);

    char* ws = (char*)d_ws;
    size_t off = 0;
    auto alloc = [&](size_t bytes) -> char* {
        char* p = ws + off;
        off += (bytes + 255) & ~(size_t)255;
        return p;
    };
    unsigned short* xb16  = (unsigned short*)alloc(X_ELEMS * 2);
    unsigned short* ipb16[2];
    ipb16[0] = (unsigned short*)alloc(IP_ELEMS * 2);
    ipb16[1] = (unsigned short*)alloc(IP_ELEMS * 2);
    unsigned short* Ebuf  = (unsigned short*)alloc(2 * 512 * 1024 * 2);
    unsigned short* Ef    = Ebuf;
    unsigned short* Eb    = Ebuf + 512 * 1024;
    unsigned short* xbcdt = (unsigned short*)alloc(R * 1072 * 2);
    unsigned short* ybuf  = xbcdt;                       // alias (xbcdt dead by scan_out)
    unsigned short* xconv = (unsigned short*)alloc(R * 1056 * 2);
    unsigned short* zbuf  = xconv;                       // alias (xconv dead after scans)
    float* fbuf = (float*)alloc(R * 512 * 4);
    float* dtb  = (float*)alloc(R * 16 * 4);
    float* dab  = (float*)alloc(R * 16 * 4);
    float* Hbuf = (float*)alloc(R * 1024);
    float* dec  = (float*)alloc((size_t)g * 1024 * 4);

    dim3 blk(256);

    cvt_k<<<(unsigned)((X_ELEMS / 8 + 255) / 256), blk, 0, stream>>>(x, xb16, (int)(X_ELEMS / 8));
    cvt_k<<<(unsigned)((IP_ELEMS / 8 + 255) / 256), blk, 0, stream>>>(in_proj[0], ipb16[0], (int)(IP_ELEMS / 8));
    cvt_k<<<(unsigned)((IP_ELEMS / 8 + 255) / 256), blk, 0, stream>>>(in_proj[1], ipb16[1], (int)(IP_ELEMS / 8));
    eprep_k<<<512, blk, 0, stream>>>(proj_w, out_proj[0], Ef, 0);
    eprep_k<<<512, blk, 0, stream>>>(proj_w, out_proj[1], Eb, 512);

    for (int grp = 0; grp < nGroups; grp++) {
        const unsigned short* xg = xb16 + (size_t)grp * R * 512;
        const float* xgf = x + (size_t)grp * R * 512;
        float* og = outp + (size_t)grp * R * 512;

        for (int dir = 0; dir < 2; dir++) {
            if (dir == 0)
                gemm_bt<false, false, false, false, false><<<dim3(9, MT), blk, 0, stream>>>(
                    xg, ipb16[0] + (size_t)1024 * 512, xbcdt, nullptr, 1072, 512, 1072, 0);
            else
                gemm_bt<true, false, false, false, false><<<dim3(9, MT), blk, 0, stream>>>(
                    xg, ipb16[1] + (size_t)1024 * 512, xbcdt, nullptr, 1072, 512, 1072, 0);

            conv_silu_k<<<(unsigned)(R * 132 / 2048), blk, 0, stream>>>(xbcdt, conv_w[dir], conv_b[dir], xconv);
            dt_pre_k<<<(unsigned)(R * 16 / 256), blk, 0, stream>>>(xbcdt, dt_bias[dir], A_log[dir], dtb, dab);

            scan_state_k<<<(unsigned)(R / 4), dim3(64), 0, stream>>>(xconv, dtb, dab, Hbuf, dec);
            scan_comb_k<<<(unsigned)(g * 16), dim3(64), 0, stream>>>(Hbuf, dec);
            scan_out_k<<<(unsigned)(R / 4), dim3(64), 0, stream>>>(xconv, dtb, dab, Hbuf, Dp[dir], ybuf);

            if (dir == 0)
                gemm_bt<false, false, false, false, false><<<dim3(8, MT), blk, 0, stream>>>(
                    xg, ipb16[0], zbuf, nullptr, 1024, 512, 1024, 0);
            else
                gemm_bt<true, false, false, false, false><<<dim3(8, MT), blk, 0, stream>>>(
                    xg, ipb16[1], zbuf, nullptr, 1024, 512, 1024, 0);

            rmsgate_k<<<(unsigned)R, blk, 0, stream>>>(ybuf, zbuf, norm_w[dir]);

            if (dir == 0)
                gemm_bt<false, false, true, true, false><<<dim3(4, MT), blk, 0, stream>>>(
                    ybuf, Ef, fbuf, proj_b, 512, 1024, 512, 0);
            else
                gemm_bt<false, true, true, false, true><<<dim3(4, MT), blk, 0, stream>>>(
                    ybuf, Eb, fbuf, nullptr, 512, 1024, 512, 0);
        }
        ln_k<<<(unsigned)R, dim3(128), 0, stream>>>(xgf, fbuf, ln_w, ln_b, og);
    }
}